// Round 1
// baseline (365.709 us; speedup 1.0000x reference)
//
#include <hip/hip_runtime.h>

typedef __attribute__((ext_vector_type(4))) float f32x4;
typedef __attribute__((ext_vector_type(8))) short short8;

#define B_ 4
#define N_ 8192
#define E_ 131072
#define R_ 16
#define H_ 128
#define OUT_ 32
#define NKEYS (B_*N_*R_)   /* 524288 */
#define NEDGE (B_*E_)      /* 524288 */

__device__ __forceinline__ unsigned short f2bf(float f){
  unsigned int u = __float_as_uint(f);
  u = (u + 0x7fffu + ((u>>16)&1u)) >> 16;
  return (unsigned short)u;
}
__device__ __forceinline__ float bf2f(unsigned short s){
  return __uint_as_float(((unsigned int)s)<<16);
}

__global__ void zero_k(int* __restrict__ p){
  p[blockIdx.x*256 + threadIdx.x] = 0;
}

__global__ void hist_k(const int* __restrict__ et, const int* __restrict__ ec,
                       int* __restrict__ cnt){
  int e = blockIdx.x*256 + threadIdx.x;
  int b = e >> 17;                  // E = 2^17
  int dst = et[2*e+1];
  int r  = ec[e];
  atomicAdd(&cnt[(((b<<13)+dst)<<4)+r], 1);
}

__global__ void scan1_k(const int* __restrict__ in, int* __restrict__ out,
                        int* __restrict__ bsum){
  __shared__ int lds[256];
  int t = threadIdx.x;
  int base = blockIdx.x*1024 + t*4;
  int4 v = *(const int4*)(in + base);
  lds[t] = v.x+v.y+v.z+v.w;
  __syncthreads();
  for (int off=1; off<256; off<<=1){
    int x = (t>=off) ? lds[t-off] : 0;
    __syncthreads();
    lds[t] += x;
    __syncthreads();
  }
  if (t==255) bsum[blockIdx.x] = lds[255];
  int pre = (t==0) ? 0 : lds[t-1];
  int4 o;
  o.x = pre; o.y = o.x+v.x; o.z = o.y+v.y; o.w = o.z+v.z;
  *(int4*)(out + base) = o;
}

__global__ void scan2_k(int* __restrict__ bsum){
  __shared__ int lds[256];
  int t = threadIdx.x;
  int2 v = *(const int2*)(bsum + t*2);
  lds[t] = v.x+v.y;
  __syncthreads();
  for (int off=1; off<256; off<<=1){
    int x = (t>=off) ? lds[t-off] : 0;
    __syncthreads();
    lds[t] += x;
    __syncthreads();
  }
  int pre = (t==0) ? 0 : lds[t-1];
  int2 o; o.x = pre; o.y = pre + v.x;
  *(int2*)(bsum + t*2) = o;
}

__global__ void scan3_k(int* __restrict__ out, const int* __restrict__ bsum){
  int t = threadIdx.x;
  int base = blockIdx.x*1024 + t*4;
  int add = bsum[blockIdx.x];
  int4 v = *(int4*)(out + base);
  v.x+=add; v.y+=add; v.z+=add; v.w+=add;
  *(int4*)(out + base) = v;
  if (blockIdx.x==0 && t==0) out[NKEYS] = NEDGE;
}

__global__ void fill_k(const int* __restrict__ et, const int* __restrict__ ec,
                       const float* __restrict__ me, const int* __restrict__ off,
                       int* __restrict__ cur, unsigned short* __restrict__ esrc,
                       float* __restrict__ emask){
  int e = blockIdx.x*256 + threadIdx.x;
  int b = e >> 17;
  int src = et[2*e];
  int dst = et[2*e+1];
  int r  = ec[e];
  int key = (((b<<13)+dst)<<4)+r;
  int pos = off[key] + atomicAdd(&cur[key], 1);
  esrc[pos] = (unsigned short)src;
  emask[pos] = me[e];
}

__global__ void embed_k(const int* __restrict__ cls, const float* __restrict__ emb,
                        unsigned short* __restrict__ h){
  int t = blockIdx.x*256 + threadIdx.x;   // B*N*32 threads, 4 feats each
  int node = t>>5, c = t&31;
  int cl = cls[node];
  float4 v = *(const float4*)(emb + cl*H_ + c*4);
  uint2 o;
  o.x = f2bf(v.x) | ((unsigned int)f2bf(v.y)<<16);
  o.y = f2bf(v.z) | ((unsigned int)f2bf(v.w)<<16);
  *(uint2*)(h + node*H_ + c*4) = o;
}

// Wt[r][n][k] = bf16(W[r][k][n])   (k-contiguous so B-fragments are 16B loads)
__global__ void wtrans_k(const float* __restrict__ W, unsigned short* __restrict__ Wt,
                         int nout, int total){
  int t = blockIdx.x*256 + threadIdx.x;
  if (t >= total) return;
  int k = t & 127;
  int n = (t>>7) % nout;
  int r = t / (128*nout);
  Wt[t] = f2bf(W[(r*H_ + k)*nout + n]);
}

// One block = 128 dst rows of one batch. Per relation r: build A-tile
// (fp32 reg accumulation of mask*h[src], bf16 into XOR-swizzled LDS), then
// MFMA against Wt[r]. out = Sum_r A_r @ W_r.
template<int NOUT, int WM, int WN>
__global__ __launch_bounds__(512) void layer_k(
    const unsigned short* __restrict__ h_in,   // bf16 [B*N*H]
    const unsigned short* __restrict__ Wt,     // bf16 [R][NOUT][H]
    const int* __restrict__ csr_off,
    const unsigned short* __restrict__ esrc,
    const float* __restrict__ emask,
    unsigned short* __restrict__ h_out,        // bf16 relu'd (NOUT=128)
    float* __restrict__ logits)                // fp32 (NOUT=32)
{
  constexpr int MI = 128/(16*WM);
  constexpr int NI = NOUT/(16*WN);
  __shared__ __align__(16) unsigned short A_lds[128*128];  // 32KB bf16, swizzled

  const int tid  = threadIdx.x;
  const int wave = tid>>6, lane = tid&63;
  const int b    = blockIdx.x>>6, dt = blockIdx.x&63;
  const int dst0 = dt<<7;
  const int wm = wave / WN, wn = wave % WN;

  f32x4 acc[MI][NI];
  #pragma unroll
  for (int i=0;i<MI;i++)
    #pragma unroll
    for (int j=0;j<NI;j++)
      acc[i][j] = f32x4{0.f,0.f,0.f,0.f};

  const int row = tid>>2, q = tid&3;                 // A-build: 4 threads/row
  const int keybase = (((b<<13) + dst0 + row)<<4);
  const unsigned int sw_w = (unsigned int)((row&7)<<4);
  const unsigned int rowbase = (unsigned int)(row*256);

  for (int r=0;r<R_;r++){
    __syncthreads();                                  // protect A_lds reuse
    // ---- build A rows: fp32 accumulate 32 features of this (row, r) ----
    float fa[32];
    #pragma unroll
    for (int i=0;i<32;i++) fa[i]=0.f;
    int s0 = csr_off[keybase + r];
    int s1 = csr_off[keybase + r + 1];
    for (int p=s0;p<s1;p++){
      int src = esrc[p];
      float m = emask[p];
      const short8* hp = (const short8*)(h_in + (((b<<13)+src)<<7) + q*32);
      #pragma unroll
      for (int c=0;c<4;c++){
        short8 hv = hp[c];
        #pragma unroll
        for (int j=0;j<8;j++)
          fa[c*8+j] += m * bf2f((unsigned short)hv[j]);
      }
    }
    #pragma unroll
    for (int c=0;c<4;c++){
      uint4 pk;
      pk.x = f2bf(fa[c*8+0]) | ((unsigned int)f2bf(fa[c*8+1])<<16);
      pk.y = f2bf(fa[c*8+2]) | ((unsigned int)f2bf(fa[c*8+3])<<16);
      pk.z = f2bf(fa[c*8+4]) | ((unsigned int)f2bf(fa[c*8+5])<<16);
      pk.w = f2bf(fa[c*8+6]) | ((unsigned int)f2bf(fa[c*8+7])<<16);
      unsigned int byte = rowbase + (((unsigned int)(q*64 + c*16)) ^ sw_w);
      *(uint4*)((char*)A_lds + byte) = pk;
    }
    __syncthreads();

    // ---- MFMA: 4 K-steps of 32 over this relation ----
    #pragma unroll
    for (int ks=0;ks<4;ks++){
      const int k0 = ks*32;
      short8 af[MI];
      #pragma unroll
      for (int mi=0;mi<MI;mi++){
        int m = wm*(MI*16) + mi*16 + (lane&15);
        unsigned int byte = (unsigned int)(m*256) +
            ((unsigned int)((k0 + ((lane>>4)<<3))*2) ^ (unsigned int)((m&7)<<4));
        af[mi] = *(const short8*)((const char*)A_lds + byte);
      }
      #pragma unroll
      for (int ni=0;ni<NI;ni++){
        int n = wn*(NI*16) + ni*16 + (lane&15);
        short8 bfr = *(const short8*)(Wt + ((r*NOUT + n)<<7) + k0 + ((lane>>4)<<3));
        #pragma unroll
        for (int mi=0;mi<MI;mi++)
          acc[mi][ni] = __builtin_amdgcn_mfma_f32_16x16x32_bf16(af[mi], bfr, acc[mi][ni], 0,0,0);
      }
    }
  }

  // ---- epilogue: D layout col=lane&15, row=(lane>>4)*4+j (m89-verified) ----
  #pragma unroll
  for (int mi=0;mi<MI;mi++){
    #pragma unroll
    for (int ni=0;ni<NI;ni++){
      int n = wn*(NI*16) + ni*16 + (lane&15);
      #pragma unroll
      for (int j=0;j<4;j++){
        int m = wm*(MI*16) + mi*16 + ((lane>>4)<<2) + j;
        float v = acc[mi][ni][j];
        int idx = ((b<<13) + dst0 + m)*NOUT + n;
        if (NOUT==128){
          h_out[idx] = f2bf(fmaxf(v, 0.f));
        } else {
          logits[idx] = v;
        }
      }
    }
  }
}

__global__ void softmax_k(const float* __restrict__ logits,
                          const float* __restrict__ mobj,
                          float* __restrict__ out){
  int row = blockIdx.x*256 + threadIdx.x;  // 32768 rows
  float v[32];
  const float4* p = (const float4*)(logits + row*32);
  #pragma unroll
  for (int i=0;i<8;i++){
    float4 x = p[i];
    v[4*i]=x.x; v[4*i+1]=x.y; v[4*i+2]=x.z; v[4*i+3]=x.w;
  }
  float mx = v[0];
  #pragma unroll
  for (int i=1;i<32;i++) mx = fmaxf(mx, v[i]);
  float s = 0.f;
  #pragma unroll
  for (int i=0;i<32;i++){ v[i] = __expf(v[i]-mx); s += v[i]; }
  float sc = mobj[row] / s;
  float4* qo = (float4*)(out + row*32);
  #pragma unroll
  for (int i=0;i<8;i++){
    float4 x;
    x.x=v[4*i]*sc; x.y=v[4*i+1]*sc; x.z=v[4*i+2]*sc; x.w=v[4*i+3]*sc;
    qo[i] = x;
  }
}

extern "C" void kernel_launch(void* const* d_in, const int* in_sizes, int n_in,
                              void* d_out, int out_size, void* d_ws, size_t ws_size,
                              hipStream_t stream){
  const int*   cls   = (const int*)  d_in[0];
  // d_in[1] states_objects: unused by reference
  const int*   et    = (const int*)  d_in[2];
  const int*   ec    = (const int*)  d_in[3];
  const float* mobj  = (const float*)d_in[4];
  const float* medge = (const float*)d_in[5];
  const float* emb   = (const float*)d_in[6];
  const float* W1    = (const float*)d_in[7];
  const float* W2    = (const float*)d_in[8];
  const float* W3    = (const float*)d_in[9];
  float* out = (float*)d_out;

  char* ws = (char*)d_ws;
  size_t o = 0;
  auto alloc = [&](size_t bytes)->char*{
    char* p = ws + o;
    o += (bytes + 255) & ~(size_t)255;
    return p;
  };
  unsigned short* hA    = (unsigned short*)alloc((size_t)B_*N_*H_*2);
  unsigned short* hB    = (unsigned short*)alloc((size_t)B_*N_*H_*2);
  float*          lg    = (float*)alloc((size_t)B_*N_*OUT_*4);
  unsigned short* W1t   = (unsigned short*)alloc((size_t)R_*H_*H_*2);
  unsigned short* W2t   = (unsigned short*)alloc((size_t)R_*H_*H_*2);
  unsigned short* W3t   = (unsigned short*)alloc((size_t)R_*OUT_*H_*2);
  int*            cnt   = (int*)alloc((size_t)NKEYS*4);
  int*            off   = (int*)alloc((size_t)(NKEYS+1)*4);
  int*            bsum  = (int*)alloc(512*4);
  unsigned short* esrc  = (unsigned short*)alloc((size_t)NEDGE*2);
  float*          emask = (float*)alloc((size_t)NEDGE*4);
  (void)ws_size; (void)in_sizes; (void)n_in; (void)out_size;

  // CSR build: histogram -> exclusive scan -> fill
  hipLaunchKernelGGL(zero_k,  dim3(NKEYS/256), dim3(256), 0, stream, cnt);
  hipLaunchKernelGGL(hist_k,  dim3(NEDGE/256), dim3(256), 0, stream, et, ec, cnt);
  hipLaunchKernelGGL(scan1_k, dim3(512), dim3(256), 0, stream, cnt, off, bsum);
  hipLaunchKernelGGL(scan2_k, dim3(1),   dim3(256), 0, stream, bsum);
  hipLaunchKernelGGL(scan3_k, dim3(512), dim3(256), 0, stream, off, bsum);
  hipLaunchKernelGGL(zero_k,  dim3(NKEYS/256), dim3(256), 0, stream, cnt);  // cnt -> cursor
  hipLaunchKernelGGL(fill_k,  dim3(NEDGE/256), dim3(256), 0, stream, et, ec, medge, off, cnt, esrc, emask);

  // h0 = bf16(embed[class]);  W -> bf16 [r][n][k]
  hipLaunchKernelGGL(embed_k, dim3(B_*N_*32/256), dim3(256), 0, stream, cls, emb, hA);
  hipLaunchKernelGGL(wtrans_k, dim3(R_*H_*H_/256),   dim3(256), 0, stream, W1, W1t, H_,   R_*H_*H_);
  hipLaunchKernelGGL(wtrans_k, dim3(R_*H_*H_/256),   dim3(256), 0, stream, W2, W2t, H_,   R_*H_*H_);
  hipLaunchKernelGGL(wtrans_k, dim3(R_*OUT_*H_/256), dim3(256), 0, stream, W3, W3t, OUT_, R_*OUT_*H_);

  // 3 fused aggregate+GEMM layers, then softmax*mask
  hipLaunchKernelGGL((layer_k<128,2,4>), dim3(256), dim3(512), 0, stream,
                     hA, W1t, off, esrc, emask, hB, (float*)nullptr);
  hipLaunchKernelGGL((layer_k<128,2,4>), dim3(256), dim3(512), 0, stream,
                     hB, W2t, off, esrc, emask, hA, (float*)nullptr);
  hipLaunchKernelGGL((layer_k<32,8,1>),  dim3(256), dim3(512), 0, stream,
                     hA, W3t, off, esrc, emask, (unsigned short*)nullptr, lg);
  hipLaunchKernelGGL(softmax_k, dim3(B_*N_/256), dim3(256), 0, stream, lg, mobj, out);
}